// Round 5
// baseline (576.245 us; speedup 1.0000x reference)
//
#include <hip/hip_runtime.h>

// FMLayer: out[b, p] = <w[j1], w[j2]> * x[b, j1] * x[b, j2] for triu pairs (j1<j2)
// N=512, K=4, B=1024, P=130816. Inputs fp32, output fp32.
//
// R7: grid-stride "fill-clone" writer.
// Post-mortem R5/R6: per-block private 262KB streams plateau at 2.4-2.8 TB/s
// regardless of store flavor (NT/plain), vector width, VALU load, or LDS
// conflicts -> the limiter is the WRITE ADDRESS PATTERN. The harness's
// fillBufferAligned proves 6.2 TB/s at ~10% occupancy using a grid-stride
// sweep: all waves form one dense ~8MB window advancing linearly (per-wave
// consecutive stores are MBs apart). We clone that exactly:
//  - grid-stride loop over flat [B*P] in groups of 4 floats, f32x4 plain store
//    (same grid shape / stride / store width as the fill).
//  - wd[p] table (523 KB, d_ws, L2-resident) loaded f32x4 stride-1.
//  - x read straight through L1/L2 (2 MB; wave-local row reuse). No LDS, no
//    barrier anywhere.
//  - j1 via sqrt + exact fixup (validated R5); slow path only when a 4-group
//    crosses a triangle-row boundary (<2% of groups).

#define NF      512
#define KDIM    4
#define BATCH   1024
#define NPAIRS  130816            // 512*511/2
#define WDPAD   131072            // NPAIRS padded (+256 entries)
#define TPB     256
#define NBLK    2048              // 8 blocks/CU, like the fill
#define NGROUPS 33488896          // BATCH*NPAIRS/4
#define GSTRIDE (NBLK * TPB)      // 524288 threads
#define BT      16                // fallback path only

typedef float f32x4 __attribute__((ext_vector_type(4)));

__device__ __forceinline__ int rowoff(int j) {
    return (j * (1023 - j)) >> 1;      // start offset of row j1=j
}

// ---------- kernel 1: wdot table (523 KB) + pad ----------
__global__ __launch_bounds__(TPB) void fm_wdot(
    const float* __restrict__ w,     // [NF, KDIM]
    float* __restrict__ wd)          // [WDPAD]
{
    const int j1 = blockIdx.x;
    if (j1 == NF - 1) {              // pad block: zero [NPAIRS, WDPAD)
        wd[NPAIRS + threadIdx.x] = 0.f;
        return;
    }
    const int L   = (NF - 1) - j1;
    const int off = rowoff(j1);
    const float wa0 = w[j1*KDIM+0], wa1 = w[j1*KDIM+1],
                wa2 = w[j1*KDIM+2], wa3 = w[j1*KDIM+3];
    for (int t = threadIdx.x; t < L; t += TPB) {
        const int j2 = j1 + 1 + t;
        wd[off + t] = wa0*w[j2*KDIM+0] + wa1*w[j2*KDIM+1]
                    + wa2*w[j2*KDIM+2] + wa3*w[j2*KDIM+3];
    }
}

// ---------- kernel 2: grid-stride fill-clone main ----------
__global__ __launch_bounds__(TPB) void fm_main4(
    const float* __restrict__ x,     // [BATCH, NF]
    const float* __restrict__ wd,    // [WDPAD]
    float* __restrict__ out)         // [BATCH*NPAIRS] flat
{
    const unsigned t0 = blockIdx.x * TPB + threadIdx.x;

    for (unsigned g = t0; g < NGROUPS; g += GSTRIDE) {
        const unsigned i = g << 2;            // flat element index (i % 4 == 0)
        const unsigned b = i / NPAIRS;        // magic-mul div by constant
        const int p = (int)(i - b * NPAIRS);  // p % 4 == 0 (NPAIRS % 4 == 0)

        // wd load first (addr ready immediately; latency hides under index math)
        const f32x4 wv = *reinterpret_cast<const f32x4*>(wd + p);

        // j1 = floor((1023 - sqrt(1023^2 - 8p))/2), exact after fixup (R5-proven)
        const float s = sqrtf((float)(1046529 - 8 * p));
        int j1 = (int)((1023.0f - s) * 0.5f);
        j1 = j1 < 0 ? 0 : (j1 > 510 ? 510 : j1);
        int len = 511 - j1;
        int r   = rowoff(j1);
        while (r > p)        { --j1; ++len; r -= len; }
        while (p >= r + len) { r += len; --len; ++j1; }

        const float* __restrict__ xrow = x + (size_t)b * NF;
        const int k = p - r;                  // position within triangle row
        f32x4 o;
        if (k + 3 < len) {                    // common: group inside one row
            const float xj1 = xrow[j1];
            const int j2 = j1 + 1 + k;
            o.x = wv.x * xj1 * xrow[j2];
            o.y = wv.y * xj1 * xrow[j2 + 1];
            o.z = wv.z * xj1 * xrow[j2 + 2];
            o.w = wv.w * xj1 * xrow[j2 + 3];
        } else {                              // rare: crosses row boundary
            int rr = r, ll = len, jj = j1;
            float tmp[4];
#pragma unroll
            for (int e = 0; e < 4; ++e) {
                while (p + e >= rr + ll) { rr += ll; --ll; ++jj; }
                const int j2 = p + e - rr + jj + 1;
                const float wde = (e == 0) ? wv.x : (e == 1) ? wv.y
                                : (e == 2) ? wv.z : wv.w;
                tmp[e] = wde * xrow[jj] * xrow[j2];
            }
            o.x = tmp[0]; o.y = tmp[1]; o.z = tmp[2]; o.w = tmp[3];
        }
        *reinterpret_cast<f32x4*>(out + i) = o;   // plain store, fill pattern
    }
}

// ---------- fallback (no workspace) ----------
__global__ __launch_bounds__(TPB) void fm_kernel(
    const float* __restrict__ x, const float* __restrict__ w,
    float* __restrict__ out)
{
    const int j1  = blockIdx.x;
    const int b0  = blockIdx.y * BT;
    const int L   = (NF - 1) - j1;
    const int off = j1 * (NF - 1) - (j1 * (j1 - 1)) / 2;
    const float wa0 = w[j1*KDIM+0], wa1 = w[j1*KDIM+1],
                wa2 = w[j1*KDIM+2], wa3 = w[j1*KDIM+3];
    __shared__ float wdl[NF - 1];
    for (int t = threadIdx.x; t < L; t += TPB) {
        const int j2 = j1 + 1 + t;
        wdl[t] = wa0*w[j2*KDIM+0] + wa1*w[j2*KDIM+1]
               + wa2*w[j2*KDIM+2] + wa3*w[j2*KDIM+3];
    }
    __syncthreads();
    for (int bi = 0; bi < BT; ++bi) {
        const int b = b0 + bi;
        const float xj1 = x[(size_t)b * NF + j1];
        const float* __restrict__ xrow = x + (size_t)b * NF + (j1 + 1);
        float* __restrict__ orow = out + (size_t)b * NPAIRS + off;
        for (int t = threadIdx.x; t < L; t += TPB)
            orow[t] = wdl[t] * xj1 * xrow[t];
    }
}

extern "C" void kernel_launch(void* const* d_in, const int* in_sizes, int n_in,
                              void* d_out, int out_size, void* d_ws, size_t ws_size,
                              hipStream_t stream) {
    const float* x = (const float*)d_in[0];     // [1024, 512] fp32
    const float* w = (const float*)d_in[1];     // [512, 4]   fp32
    float* out = (float*)d_out;                 // [1024, 130816] fp32

    if (ws_size >= (size_t)WDPAD * sizeof(float)) {
        float* wd = (float*)d_ws;
        fm_wdot<<<dim3(NF), TPB, 0, stream>>>(w, wd);        // 512 blocks, ~3 us
        fm_main4<<<dim3(NBLK), TPB, 0, stream>>>(x, wd, out);
    } else {
        dim3 grid(NF - 1, BATCH / BT);
        fm_kernel<<<grid, TPB, 0, stream>>>(x, w, out);
    }
}